// Round 1
// baseline (1886.223 us; speedup 1.0000x reference)
//
#include <hip/hip_runtime.h>
#include <hip/hip_bf16.h>

using bf16 = __hip_bfloat16;
typedef __attribute__((ext_vector_type(8))) short s8v;    // 8 bf16 in 4 VGPRs
typedef __attribute__((ext_vector_type(4))) float f4v;    // mfma accumulator

// ---------------------------------------------------------------- helpers
__device__ __forceinline__ void gld_lds16(const void* g, void* l) {
  __builtin_amdgcn_global_load_lds(
      (const __attribute__((address_space(1))) void*)g,
      (__attribute__((address_space(3))) void*)l, 16, 0, 0);
}

// ------------------------------------------------------- convert f32->bf16
__global__ __launch_bounds__(256) void f32_to_bf16_k(const float* __restrict__ in,
                                                     bf16* __restrict__ out, size_t n) {
  const size_t i = ((size_t)blockIdx.x * 256 + threadIdx.x) * 4;
  if (i + 3 < n) {
    const float4 v = *(const float4*)(in + i);
    out[i + 0] = __float2bfloat16(v.x);
    out[i + 1] = __float2bfloat16(v.y);
    out[i + 2] = __float2bfloat16(v.z);
    out[i + 3] = __float2bfloat16(v.w);
  }
}

// ------------------------------------------- tiled transpose f32 -> bf16
// out[c][r] = in[r][c]; out row stride = R. Requires R,C multiples of 32.
__global__ __launch_bounds__(256) void tr_to_bf16_k(const float* __restrict__ in,
                                                    bf16* __restrict__ out,
                                                    int R, int C,
                                                    size_t inb, size_t outb) {
  __shared__ float tile[32][33];
  in  += (size_t)blockIdx.z * inb;
  out += (size_t)blockIdx.z * outb;
  const int r0 = blockIdx.y * 32, c0 = blockIdx.x * 32;
  const int tx = threadIdx.x & 31, ty = threadIdx.x >> 5;   // 32 x 8
#pragma unroll
  for (int i = 0; i < 4; ++i)
    tile[ty + i * 8][tx] = in[(size_t)(r0 + ty + i * 8) * C + c0 + tx];
  __syncthreads();
#pragma unroll
  for (int i = 0; i < 4; ++i)
    out[(size_t)(c0 + ty + i * 8) * R + r0 + tx] = __float2bfloat16(tile[tx][ty + i * 8]);
}

// --------------------------------------------------------- bf16 MFMA GEMM
// C[m][n] = sum_k A[m][k] * Bt[n][k];  A: MxK row-major bf16, Bt: NxK row-major bf16.
// MODE 0: scale cols<1024 by 0.125, f32 out (QKV).  MODE 1: +bias, f32 out.
// MODE 2: +bias, relu, bf16 out.
template <int MODE>
__global__ __launch_bounds__(256, 2) void gemm_bt(const bf16* __restrict__ A,
                                                  const bf16* __restrict__ B,
                                                  const float* __restrict__ bias,
                                                  float* __restrict__ Cf,
                                                  bf16* __restrict__ Cb,
                                                  int M, int N, int K) {
  __shared__ __attribute__((aligned(16))) bf16 As[128 * 32];
  __shared__ __attribute__((aligned(16))) bf16 Bs[128 * 32];
  const int tid  = threadIdx.x;
  const int wid  = tid >> 6;
  const int lane = tid & 63;
  const int quad = lane >> 4;
  const int l16  = lane & 15;
  const int bm = blockIdx.y * 128;
  const int bn = blockIdx.x * 128;
  const int wm = (wid >> 1) * 64;
  const int wn = (wid & 1) * 64;

  f4v acc[4][4];
#pragma unroll
  for (int i = 0; i < 4; ++i)
#pragma unroll
    for (int j = 0; j < 4; ++j) acc[i][j] = (f4v){0.f, 0.f, 0.f, 0.f};

  // staging: wave w covers 32 rows (2 chunks of 16); lane i -> row i/4, k-off (i&3)*8
  const bf16* Ag = A + (size_t)(bm + wid * 32 + (lane >> 2)) * K + (lane & 3) * 8;
  const bf16* Bg = B + (size_t)(bn + wid * 32 + (lane >> 2)) * K + (lane & 3) * 8;
  bf16* AsW = As + wid * 32 * 32;
  bf16* BsW = Bs + wid * 32 * 32;

  for (int k0 = 0; k0 < K; k0 += 32) {
    __syncthreads();
    gld_lds16(Ag,                 AsW);
    gld_lds16(Ag + (size_t)16 * K, AsW + 16 * 32);
    gld_lds16(Bg,                 BsW);
    gld_lds16(Bg + (size_t)16 * K, BsW + 16 * 32);
    Ag += 32; Bg += 32;
    __syncthreads();

    s8v af[4], bfr[4];
#pragma unroll
    for (int mi = 0; mi < 4; ++mi)
      af[mi] = *(const s8v*)(As + (wm + mi * 16 + l16) * 32 + quad * 8);
#pragma unroll
    for (int ni = 0; ni < 4; ++ni)
      bfr[ni] = *(const s8v*)(Bs + (wn + ni * 16 + l16) * 32 + quad * 8);
#pragma unroll
    for (int mi = 0; mi < 4; ++mi)
#pragma unroll
      for (int ni = 0; ni < 4; ++ni)
        acc[mi][ni] = __builtin_amdgcn_mfma_f32_16x16x32_bf16(af[mi], bfr[ni], acc[mi][ni], 0, 0, 0);
  }

  const size_t ldc = (size_t)N;
#pragma unroll
  for (int mi = 0; mi < 4; ++mi) {
#pragma unroll
    for (int ni = 0; ni < 4; ++ni) {
      const int col = bn + wn + ni * 16 + l16;
      float bv = 0.f;
      if (MODE != 0) bv = bias[col];
#pragma unroll
      for (int r = 0; r < 4; ++r) {
        const int row = bm + wm + mi * 16 + quad * 4 + r;
        float v = acc[mi][ni][r];
        if (MODE == 0) {
          v *= (col < 1024) ? 0.125f : 1.0f;
          Cf[(size_t)row * ldc + col] = v;
        } else if (MODE == 1) {
          Cf[(size_t)row * ldc + col] = v + bv;
        } else {
          v = fmaxf(v + bv, 0.f);
          Cb[(size_t)row * ldc + col] = __float2bfloat16(v);
        }
      }
    }
  }
}

// -------------------------------------------------- fp32 flash attention
// qkv: rows (b*2048+t), 3072 cols: [q(1024, pre-scaled by 0.125) | k(1024) | v(1024)]
// o: bf16 (b*2048+t, 1024) with head h at cols h*64..h*64+63
__global__ __launch_bounds__(256, 2) void attn_fp32(const float* __restrict__ qkv,
                                                    bf16* __restrict__ o) {
  __shared__ __attribute__((aligned(16))) float Qs[64][64];
  __shared__ __attribute__((aligned(16))) float KsT[64][64];  // [d][key]
  __shared__ __attribute__((aligned(16))) float Vs[64][64];   // [key][d]
  __shared__ __attribute__((aligned(16))) float Ps[64][64];   // [row][key]

  const int tid = threadIdx.x;
  const int qt = blockIdx.x, h = blockIdx.y, b = blockIdx.z;
  const size_t base = ((size_t)b * 2048) * 3072 + (size_t)h * 64;
  const float* qb = qkv + base;
  const float* kb = qkv + base + 1024;
  const float* vb = qkv + base + 2048;

  {
    const int r = tid >> 2, c0 = (tid & 3) * 16;
    const float* src = qb + (size_t)(qt * 64 + r) * 3072 + c0;
#pragma unroll
    for (int i = 0; i < 4; ++i)
      *(float4*)&Qs[r][c0 + i * 4] = *(const float4*)(src + i * 4);
  }

  const int ri = tid >> 4;   // 0..15 -> rows ri*4..+3
  const int ci = tid & 15;   // 0..15 -> keys/dims ci*4..+3

  float m_run[4], l_run[4], oacc[4][4];
#pragma unroll
  for (int a = 0; a < 4; ++a) {
    m_run[a] = -3.0e38f; l_run[a] = 0.f;
#pragma unroll
    for (int d = 0; d < 4; ++d) oacc[a][d] = 0.f;
  }

  for (int kt = 0; kt <= qt; ++kt) {
    __syncthreads();
    {
      const int r = tid >> 2, c0 = (tid & 3) * 16;
      const float* ks = kb + (size_t)(kt * 64 + r) * 3072 + c0;
      const float* vs = vb + (size_t)(kt * 64 + r) * 3072 + c0;
#pragma unroll
      for (int i = 0; i < 4; ++i) {
        const float4 kv = *(const float4*)(ks + i * 4);
        KsT[c0 + i * 4 + 0][r] = kv.x;
        KsT[c0 + i * 4 + 1][r] = kv.y;
        KsT[c0 + i * 4 + 2][r] = kv.z;
        KsT[c0 + i * 4 + 3][r] = kv.w;
        *(float4*)&Vs[r][c0 + i * 4] = *(const float4*)(vs + i * 4);
      }
    }
    __syncthreads();

    float s[4][4];
#pragma unroll
    for (int a = 0; a < 4; ++a)
#pragma unroll
      for (int bb = 0; bb < 4; ++bb) s[a][bb] = 0.f;

    for (int d = 0; d < 64; d += 4) {
      float4 qv[4], kv[4];
#pragma unroll
      for (int a = 0; a < 4; ++a) qv[a] = *(const float4*)&Qs[ri * 4 + a][d];
#pragma unroll
      for (int i = 0; i < 4; ++i) kv[i] = *(const float4*)&KsT[d + i][ci * 4];
#pragma unroll
      for (int a = 0; a < 4; ++a) {
        s[a][0] += qv[a].x * kv[0].x + qv[a].y * kv[1].x + qv[a].z * kv[2].x + qv[a].w * kv[3].x;
        s[a][1] += qv[a].x * kv[0].y + qv[a].y * kv[1].y + qv[a].z * kv[2].y + qv[a].w * kv[3].y;
        s[a][2] += qv[a].x * kv[0].z + qv[a].y * kv[1].z + qv[a].z * kv[2].z + qv[a].w * kv[3].z;
        s[a][3] += qv[a].x * kv[0].w + qv[a].y * kv[1].w + qv[a].z * kv[2].w + qv[a].w * kv[3].w;
      }
    }

    if (kt == qt) {
#pragma unroll
      for (int a = 0; a < 4; ++a)
#pragma unroll
        for (int bb = 0; bb < 4; ++bb)
          if (ci * 4 + bb > ri * 4 + a) s[a][bb] = -3.0e38f;
    }

#pragma unroll
    for (int a = 0; a < 4; ++a) {
      float mt = fmaxf(fmaxf(s[a][0], s[a][1]), fmaxf(s[a][2], s[a][3]));
#pragma unroll
      for (int off = 1; off < 16; off <<= 1) mt = fmaxf(mt, __shfl_xor(mt, off, 16));
      const float mnew = fmaxf(m_run[a], mt);
      const float alpha = __expf(m_run[a] - mnew);
      m_run[a] = mnew;
      float4 pv;
      pv.x = __expf(s[a][0] - mnew);
      pv.y = __expf(s[a][1] - mnew);
      pv.z = __expf(s[a][2] - mnew);
      pv.w = __expf(s[a][3] - mnew);
      float ps = pv.x + pv.y + pv.z + pv.w;
#pragma unroll
      for (int off = 1; off < 16; off <<= 1) ps += __shfl_xor(ps, off, 16);
      l_run[a] = l_run[a] * alpha + ps;
      *(float4*)&Ps[ri * 4 + a][ci * 4] = pv;
#pragma unroll
      for (int d = 0; d < 4; ++d) oacc[a][d] *= alpha;
    }
    __syncthreads();

    for (int j0 = 0; j0 < 64; j0 += 4) {
      float4 pr[4], vr[4];
#pragma unroll
      for (int a = 0; a < 4; ++a) pr[a] = *(const float4*)&Ps[ri * 4 + a][j0];
#pragma unroll
      for (int jj = 0; jj < 4; ++jj) vr[jj] = *(const float4*)&Vs[j0 + jj][ci * 4];
#pragma unroll
      for (int a = 0; a < 4; ++a) {
        oacc[a][0] += pr[a].x * vr[0].x + pr[a].y * vr[1].x + pr[a].z * vr[2].x + pr[a].w * vr[3].x;
        oacc[a][1] += pr[a].x * vr[0].y + pr[a].y * vr[1].y + pr[a].z * vr[2].y + pr[a].w * vr[3].y;
        oacc[a][2] += pr[a].x * vr[0].z + pr[a].y * vr[1].z + pr[a].z * vr[2].z + pr[a].w * vr[3].z;
        oacc[a][3] += pr[a].x * vr[0].w + pr[a].y * vr[1].w + pr[a].z * vr[2].w + pr[a].w * vr[3].w;
      }
    }
  }

#pragma unroll
  for (int a = 0; a < 4; ++a) {
    const float inv = 1.f / l_run[a];
    const size_t t = (size_t)qt * 64 + ri * 4 + a;
    bf16* dst = o + ((size_t)b * 2048 + t) * 1024 + h * 64 + ci * 4;
    dst[0] = __float2bfloat16(oacc[a][0] * inv);
    dst[1] = __float2bfloat16(oacc[a][1] * inv);
    dst[2] = __float2bfloat16(oacc[a][2] * inv);
    dst[3] = __float2bfloat16(oacc[a][3] * inv);
  }
}

// ------------------------------------------- LayerNorm(ddof=1) + residual
// xo = xres + (t - mean)/sqrt(var+eps); optionally also bf16 copy.
__global__ __launch_bounds__(256) void ln_res(const float* __restrict__ xres,
                                              const float* __restrict__ t,
                                              float* __restrict__ xo,
                                              bf16* __restrict__ xob) {
  __shared__ float red[2][4];
  const int tid = threadIdx.x;
  const size_t base = (size_t)blockIdx.x * 1024;
  float v[4];
  float s = 0.f;
#pragma unroll
  for (int i = 0; i < 4; ++i) { v[i] = t[base + tid + i * 256]; s += v[i]; }
#pragma unroll
  for (int off = 32; off > 0; off >>= 1) s += __shfl_xor(s, off, 64);
  if ((tid & 63) == 0) red[0][tid >> 6] = s;
  __syncthreads();
  const float mean = (red[0][0] + red[0][1] + red[0][2] + red[0][3]) * (1.f / 1024.f);
  float ss = 0.f;
#pragma unroll
  for (int i = 0; i < 4; ++i) { const float d = v[i] - mean; ss += d * d; }
#pragma unroll
  for (int off = 32; off > 0; off >>= 1) ss += __shfl_xor(ss, off, 64);
  if ((tid & 63) == 0) red[1][tid >> 6] = ss;
  __syncthreads();
  const float var = (red[1][0] + red[1][1] + red[1][2] + red[1][3]) * (1.f / 1023.f);
  const float rstd = rsqrtf(var + 1e-5f);
#pragma unroll
  for (int i = 0; i < 4; ++i) {
    const size_t idx = base + tid + i * 256;
    const float r = xres[idx] + (v[i] - mean) * rstd;
    xo[idx] = r;
    if (xob) xob[idx] = __float2bfloat16(r);
  }
}

// ----------------------------------------------------------------- launch
extern "C" void kernel_launch(void* const* d_in, const int* in_sizes, int n_in,
                              void* d_out, int out_size, void* d_ws, size_t ws_size,
                              hipStream_t stream) {
  const float* x  = (const float*)d_in[0];
  const float* Wq = (const float*)d_in[1];
  const float* Wk = (const float*)d_in[2];
  const float* Wv = (const float*)d_in[3];
  const float* Wo = (const float*)d_in[4];
  const float* bo = (const float*)d_in[5];
  const float* W1 = (const float*)d_in[6];
  const float* b1 = (const float*)d_in[7];
  const float* W2 = (const float*)d_in[8];
  const float* b2 = (const float*)d_in[9];
  float* out = (float*)d_out;

  char* ws = (char*)d_ws;
  float* qkv  = (float*)(ws);                     // 8192x3072 f32 (96 MB)
  bf16* x_bf  = (bf16*)(ws + 100663296);          // 16 MB
  bf16* WqkvT = (bf16*)(ws + 117440512);          // 3072x1024 bf16
  bf16* WoT   = (bf16*)(ws + 123731968);          // 1024x1024
  bf16* W1T   = (bf16*)(ws + 125829120);          // 4096x1024
  bf16* W2T   = (bf16*)(ws + 134217728);          // 1024x4096
  bf16* o_bf  = (bf16*)(ws + 142606336);          // 16 MB
  float* attn = (float*)(ws + 159383552);         // 32 MB
  float* x1   = (float*)(ws + 192937984);         // 32 MB
  bf16* x1b   = (bf16*)(ws + 226492416);          // 16 MB
  // reuse qkv region after attention is done:
  bf16* h1    = (bf16*)(ws);                      // 8192x4096 bf16 (64 MB)
  float* ff   = (float*)(ws + 67108864);          // 32 MB

  // ---- input conversions / weight packing (every call: ws is re-poisoned)
  f32_to_bf16_k<<<8192, 256, 0, stream>>>(x, x_bf, (size_t)8388608);
  tr_to_bf16_k<<<dim3(2, 32, 16), 256, 0, stream>>>(Wq, WqkvT,                1024, 64,   65536, 65536);
  tr_to_bf16_k<<<dim3(2, 32, 16), 256, 0, stream>>>(Wk, WqkvT + 1024 * 1024,  1024, 64,   65536, 65536);
  tr_to_bf16_k<<<dim3(2, 32, 16), 256, 0, stream>>>(Wv, WqkvT + 2048 * 1024,  1024, 64,   65536, 65536);
  tr_to_bf16_k<<<dim3(32, 32, 1), 256, 0, stream>>>(Wo, WoT,                  1024, 1024, 0, 0);
  tr_to_bf16_k<<<dim3(128, 32, 1), 256, 0, stream>>>(W1, W1T,                 1024, 4096, 0, 0);
  tr_to_bf16_k<<<dim3(32, 128, 1), 256, 0, stream>>>(W2, W2T,                 4096, 1024, 0, 0);

  // ---- QKV projection (q pre-scaled by 1/8)
  gemm_bt<0><<<dim3(24, 64), 256, 0, stream>>>(x_bf, WqkvT, nullptr, qkv, nullptr, 8192, 3072, 1024);

  // ---- attention
  attn_fp32<<<dim3(32, 16, 4), 256, 0, stream>>>(qkv, o_bf);

  // ---- output projection + bias
  gemm_bt<1><<<dim3(8, 64), 256, 0, stream>>>(o_bf, WoT, bo, attn, nullptr, 8192, 1024, 1024);

  // ---- x1 = x + LN(attn)  (also bf16 copy for FF input)
  ln_res<<<8192, 256, 0, stream>>>(x, attn, x1, x1b);

  // ---- FF
  gemm_bt<2><<<dim3(32, 64), 256, 0, stream>>>(x1b, W1T, b1, nullptr, h1, 8192, 4096, 1024);
  gemm_bt<1><<<dim3(8, 64), 256, 0, stream>>>(h1, W2T, b2, ff, nullptr, 8192, 1024, 4096);

  // ---- out = x1 + LN(ff)
  ln_res<<<8192, 256, 0, stream>>>(x1, ff, out, nullptr);
}

// Round 3
// 734.969 us; speedup vs baseline: 2.5664x; 2.5664x over previous
//
#include <hip/hip_runtime.h>
#include <hip/hip_bf16.h>

using bf16 = __hip_bfloat16;
typedef __attribute__((ext_vector_type(8))) short s8v;    // 8 bf16 in 4 VGPRs
typedef __attribute__((ext_vector_type(4))) float f4v;    // mfma accumulator

#define QSCALE 0.18033688011112042f   /* 0.125 * log2(e) */

// ---------------------------------------------------------------- helpers
__device__ __forceinline__ void gld_lds16(const void* g, void* l) {
  __builtin_amdgcn_global_load_lds(
      (const __attribute__((address_space(1))) void*)g,
      (__attribute__((address_space(3))) void*)l, 16, 0, 0);
}

// ------------------------------------------------------- convert f32->bf16
__global__ __launch_bounds__(256) void f32_to_bf16_k(const float* __restrict__ in,
                                                     bf16* __restrict__ out, size_t n) {
  const size_t i = ((size_t)blockIdx.x * 256 + threadIdx.x) * 4;
  if (i + 3 < n) {
    const float4 v = *(const float4*)(in + i);
    out[i + 0] = __float2bfloat16(v.x);
    out[i + 1] = __float2bfloat16(v.y);
    out[i + 2] = __float2bfloat16(v.z);
    out[i + 3] = __float2bfloat16(v.w);
  }
}

// ------------------------------------------- tiled transpose f32 -> bf16
__global__ __launch_bounds__(256) void tr_to_bf16_k(const float* __restrict__ in,
                                                    bf16* __restrict__ out,
                                                    int R, int C,
                                                    size_t inb, size_t outb) {
  __shared__ float tile[32][33];
  in  += (size_t)blockIdx.z * inb;
  out += (size_t)blockIdx.z * outb;
  const int r0 = blockIdx.y * 32, c0 = blockIdx.x * 32;
  const int tx = threadIdx.x & 31, ty = threadIdx.x >> 5;   // 32 x 8
#pragma unroll
  for (int i = 0; i < 4; ++i)
    tile[ty + i * 8][tx] = in[(size_t)(r0 + ty + i * 8) * C + c0 + tx];
  __syncthreads();
#pragma unroll
  for (int i = 0; i < 4; ++i)
    out[(size_t)(c0 + ty + i * 8) * R + r0 + tx] = __float2bfloat16(tile[tx][ty + i * 8]);
}

// --------------------------------------------------------- bf16 MFMA GEMM
// C[m][n] = sum_k A[m][k] * Bt[n][k]
// MODE 0: bf16 out, cols<1024 scaled by QSCALE (QKV, q pre-scaled for exp2 softmax)
// MODE 1: +bias, f32 out.  MODE 2: +bias, relu, bf16 out.
template <int MODE>
__global__ __launch_bounds__(256, 2) void gemm_bt(const bf16* __restrict__ A,
                                                  const bf16* __restrict__ B,
                                                  const float* __restrict__ bias,
                                                  float* __restrict__ Cf,
                                                  bf16* __restrict__ Cb,
                                                  int M, int N, int K) {
  __shared__ __attribute__((aligned(16))) bf16 As[128 * 32];
  __shared__ __attribute__((aligned(16))) bf16 Bs[128 * 32];
  const int tid  = threadIdx.x;
  const int wid  = tid >> 6;
  const int lane = tid & 63;
  const int quad = lane >> 4;
  const int l16  = lane & 15;
  const int bm = blockIdx.y * 128;
  const int bn = blockIdx.x * 128;
  const int wm = (wid >> 1) * 64;
  const int wn = (wid & 1) * 64;

  f4v acc[4][4];
#pragma unroll
  for (int i = 0; i < 4; ++i)
#pragma unroll
    for (int j = 0; j < 4; ++j) acc[i][j] = (f4v){0.f, 0.f, 0.f, 0.f};

  const bf16* Ag = A + (size_t)(bm + wid * 32 + (lane >> 2)) * K + (lane & 3) * 8;
  const bf16* Bg = B + (size_t)(bn + wid * 32 + (lane >> 2)) * K + (lane & 3) * 8;
  bf16* AsW = As + wid * 32 * 32;
  bf16* BsW = Bs + wid * 32 * 32;

  for (int k0 = 0; k0 < K; k0 += 32) {
    __syncthreads();
    gld_lds16(Ag,                  AsW);
    gld_lds16(Ag + (size_t)16 * K, AsW + 16 * 32);
    gld_lds16(Bg,                  BsW);
    gld_lds16(Bg + (size_t)16 * K, BsW + 16 * 32);
    Ag += 32; Bg += 32;
    __syncthreads();

    s8v af[4], bfr[4];
#pragma unroll
    for (int mi = 0; mi < 4; ++mi)
      af[mi] = *(const s8v*)(As + (wm + mi * 16 + l16) * 32 + quad * 8);
#pragma unroll
    for (int ni = 0; ni < 4; ++ni)
      bfr[ni] = *(const s8v*)(Bs + (wn + ni * 16 + l16) * 32 + quad * 8);
#pragma unroll
    for (int mi = 0; mi < 4; ++mi)
#pragma unroll
      for (int ni = 0; ni < 4; ++ni)
        acc[mi][ni] = __builtin_amdgcn_mfma_f32_16x16x32_bf16(af[mi], bfr[ni], acc[mi][ni], 0, 0, 0);
  }

  const size_t ldc = (size_t)N;
#pragma unroll
  for (int mi = 0; mi < 4; ++mi) {
#pragma unroll
    for (int ni = 0; ni < 4; ++ni) {
      const int col = bn + wn + ni * 16 + l16;
      float bv = 0.f;
      if (MODE != 0) bv = bias[col];
#pragma unroll
      for (int r = 0; r < 4; ++r) {
        const int row = bm + wm + mi * 16 + quad * 4 + r;
        float v = acc[mi][ni][r];
        if (MODE == 0) {
          v *= (col < 1024) ? QSCALE : 1.0f;
          Cb[(size_t)row * ldc + col] = __float2bfloat16(v);
        } else if (MODE == 1) {
          Cf[(size_t)row * ldc + col] = v + bv;
        } else {
          v = fmaxf(v + bv, 0.f);
          Cb[(size_t)row * ldc + col] = __float2bfloat16(v);
        }
      }
    }
  }
}

// -------------------------------------------------- bf16 MFMA flash attention
// qkv: bf16 rows (b*2048+t), 3072 cols: [q(64/head, pre-scaled) | k | v]
// o:   bf16 (b*2048+t, 1024), head h at cols h*64..+63
// block: 128 Q-rows of one (b,h); 4 waves x 32 rows; K-tiles of 64 keys.
__global__ __launch_bounds__(256, 2) void attn_mfma(const bf16* __restrict__ qkv,
                                                    bf16* __restrict__ o) {
  __shared__ __attribute__((aligned(16))) bf16 Ks[64 * 72];   // [key][d]
  __shared__ __attribute__((aligned(16))) bf16 Vt[64 * 72];   // [d][key]
  __shared__ __attribute__((aligned(16))) bf16 Ps[128 * 72];  // [row][key]

  const int tid  = threadIdx.x;
  const int wid  = tid >> 6;
  const int lane = tid & 63;
  const int quad = lane >> 4;
  const int l16  = lane & 15;
  const int qt = 15 - blockIdx.x;       // heavy blocks first
  const int h = blockIdx.y, b = blockIdx.z;

  const bf16* qbase = qkv + (size_t)b * 2048 * 3072 + h * 64;
  const bf16* kbase = qbase + 1024;
  const bf16* vbase = qbase + 2048;

  // Q fragments in registers: [mtile][kstep]
  s8v qf[2][2];
#pragma unroll
  for (int mt = 0; mt < 2; ++mt)
#pragma unroll
    for (int ks = 0; ks < 2; ++ks)
      qf[mt][ks] = *(const s8v*)(qbase +
          (size_t)(qt * 128 + wid * 32 + mt * 16 + l16) * 3072 + ks * 32 + quad * 8);

  float m_run[2][4], l_run[2][4];
  f4v oacc[2][4];
#pragma unroll
  for (int mt = 0; mt < 2; ++mt)
#pragma unroll
    for (int r = 0; r < 4; ++r) {
      m_run[mt][r] = -1.0e38f; l_run[mt][r] = 0.f;
    }
#pragma unroll
  for (int mt = 0; mt < 2; ++mt)
#pragma unroll
    for (int dt = 0; dt < 4; ++dt) oacc[mt][dt] = (f4v){0.f, 0.f, 0.f, 0.f};

  const int trow = tid >> 2, tseg = tid & 3;   // staging map: 4 threads/row
  const int nkt = 2 * qt + 2;
  const int wrow0 = qt * 128 + wid * 32;

  const bf16* kptr = kbase + (size_t)trow * 3072 + tseg * 16;
  const bf16* vptr = vbase + (size_t)trow * 3072 + tseg * 16;
  uint4 kreg[2], vreg[2];
  kreg[0] = *(const uint4*)(kptr);     kreg[1] = *(const uint4*)(kptr + 8);
  vreg[0] = *(const uint4*)(vptr);     vreg[1] = *(const uint4*)(vptr + 8);

  for (int kt = 0; kt < nkt; ++kt) {
    // ---- stage regs -> LDS
    *(uint4*)&Ks[trow * 72 + tseg * 16]     = kreg[0];
    *(uint4*)&Ks[trow * 72 + tseg * 16 + 8] = kreg[1];
    {
      const bf16* vv = (const bf16*)vreg;
#pragma unroll
      for (int j = 0; j < 16; ++j) {
        const int jj = (j + tseg * 4) & 15;   // row-rotate: 8-way -> 4-way banks
        Vt[(tseg * 16 + jj) * 72 + trow] = vv[jj];
      }
    }
    __syncthreads();

    // ---- prefetch next tile
    if (kt + 1 < nkt) {
      kptr += (size_t)64 * 3072; vptr += (size_t)64 * 3072;
      kreg[0] = *(const uint4*)(kptr);     kreg[1] = *(const uint4*)(kptr + 8);
      vreg[0] = *(const uint4*)(vptr);     vreg[1] = *(const uint4*)(vptr + 8);
    }

    // ---- compute (skip if this k-tile is fully masked for this wave)
    if (kt * 64 <= wrow0 + 31) {
      s8v kf[4][2];
#pragma unroll
      for (int nt = 0; nt < 4; ++nt)
#pragma unroll
        for (int ks = 0; ks < 2; ++ks)
          kf[nt][ks] = *(const s8v*)&Ks[(nt * 16 + l16) * 72 + ks * 32 + quad * 8];

      f4v sacc[2][4];
#pragma unroll
      for (int mt = 0; mt < 2; ++mt)
#pragma unroll
        for (int nt = 0; nt < 4; ++nt) sacc[mt][nt] = (f4v){0.f, 0.f, 0.f, 0.f};
#pragma unroll
      for (int mt = 0; mt < 2; ++mt)
#pragma unroll
        for (int nt = 0; nt < 4; ++nt)
#pragma unroll
          for (int ks = 0; ks < 2; ++ks)
            sacc[mt][nt] = __builtin_amdgcn_mfma_f32_16x16x32_bf16(
                qf[mt][ks], kf[nt][ks], sacc[mt][nt], 0, 0, 0);

      if (kt * 64 + 63 > wrow0) {   // diagonal: causal mask
#pragma unroll
        for (int mt = 0; mt < 2; ++mt)
#pragma unroll
          for (int nt = 0; nt < 4; ++nt)
#pragma unroll
            for (int r = 0; r < 4; ++r) {
              const int row = wrow0 + mt * 16 + quad * 4 + r;
              const int key = kt * 64 + nt * 16 + l16;
              if (key > row) sacc[mt][nt][r] = -3.0e38f;
            }
      }

      // ---- online softmax (exp2 domain; Q pre-scaled by log2(e)/8)
#pragma unroll
      for (int mt = 0; mt < 2; ++mt)
#pragma unroll
        for (int r = 0; r < 4; ++r) {
          float sm = fmaxf(fmaxf(sacc[mt][0][r], sacc[mt][1][r]),
                           fmaxf(sacc[mt][2][r], sacc[mt][3][r]));
#pragma unroll
          for (int off = 1; off < 16; off <<= 1)
            sm = fmaxf(sm, __shfl_xor(sm, off, 16));
          const float mold = m_run[mt][r];
          const float mnew = fmaxf(mold, sm);
          const float alpha = __builtin_amdgcn_exp2f(mold - mnew);
          m_run[mt][r] = mnew;
          const int lrow = wid * 32 + mt * 16 + quad * 4 + r;
          float rs = 0.f;
#pragma unroll
          for (int nt = 0; nt < 4; ++nt) {
            const float p = __builtin_amdgcn_exp2f(sacc[mt][nt][r] - mnew);
            rs += p;
            Ps[lrow * 72 + nt * 16 + l16] = __float2bfloat16(p);
          }
#pragma unroll
          for (int off = 1; off < 16; off <<= 1) rs += __shfl_xor(rs, off, 16);
          l_run[mt][r] = l_run[mt][r] * alpha + rs;
#pragma unroll
          for (int dt = 0; dt < 4; ++dt) oacc[mt][dt][r] *= alpha;
        }

      // ---- P·V (P via LDS round-trip: C-layout -> A-layout; wave-private)
#pragma unroll
      for (int ks = 0; ks < 2; ++ks) {
        s8v pf[2];
        pf[0] = *(const s8v*)&Ps[(wid * 32 +      l16) * 72 + ks * 32 + quad * 8];
        pf[1] = *(const s8v*)&Ps[(wid * 32 + 16 + l16) * 72 + ks * 32 + quad * 8];
#pragma unroll
        for (int dt = 0; dt < 4; ++dt) {
          const s8v vf = *(const s8v*)&Vt[(dt * 16 + l16) * 72 + ks * 32 + quad * 8];
          oacc[0][dt] = __builtin_amdgcn_mfma_f32_16x16x32_bf16(pf[0], vf, oacc[0][dt], 0, 0, 0);
          oacc[1][dt] = __builtin_amdgcn_mfma_f32_16x16x32_bf16(pf[1], vf, oacc[1][dt], 0, 0, 0);
        }
      }
    }
    __syncthreads();   // all waves done reading Ks/Vt before next stage
  }

  // ---- epilogue: O = oacc / l
#pragma unroll
  for (int mt = 0; mt < 2; ++mt)
#pragma unroll
    for (int r = 0; r < 4; ++r) {
      const float inv = 1.0f / l_run[mt][r];
      const size_t grow = (size_t)b * 2048 + qt * 128 + wid * 32 + mt * 16 + quad * 4 + r;
      bf16* dst = o + grow * 1024 + h * 64;
#pragma unroll
      for (int dt = 0; dt < 4; ++dt)
        dst[dt * 16 + l16] = __float2bfloat16(oacc[mt][dt][r] * inv);
    }
}

// ------------------------------------------- LayerNorm(ddof=1) + residual
__global__ __launch_bounds__(256) void ln_res(const float* __restrict__ xres,
                                              const float* __restrict__ t,
                                              float* __restrict__ xo,
                                              bf16* __restrict__ xob) {
  __shared__ float red[2][4];
  const int tid = threadIdx.x;
  const size_t base = (size_t)blockIdx.x * 1024;
  float v[4];
  float s = 0.f;
#pragma unroll
  for (int i = 0; i < 4; ++i) { v[i] = t[base + tid + i * 256]; s += v[i]; }
#pragma unroll
  for (int off = 32; off > 0; off >>= 1) s += __shfl_xor(s, off, 64);
  if ((tid & 63) == 0) red[0][tid >> 6] = s;
  __syncthreads();
  const float mean = (red[0][0] + red[0][1] + red[0][2] + red[0][3]) * (1.f / 1024.f);
  float ss = 0.f;
#pragma unroll
  for (int i = 0; i < 4; ++i) { const float d = v[i] - mean; ss += d * d; }
#pragma unroll
  for (int off = 32; off > 0; off >>= 1) ss += __shfl_xor(ss, off, 64);
  if ((tid & 63) == 0) red[1][tid >> 6] = ss;
  __syncthreads();
  const float var = (red[1][0] + red[1][1] + red[1][2] + red[1][3]) * (1.f / 1023.f);
  const float rstd = rsqrtf(var + 1e-5f);
#pragma unroll
  for (int i = 0; i < 4; ++i) {
    const size_t idx = base + tid + i * 256;
    const float r = xres[idx] + (v[i] - mean) * rstd;
    xo[idx] = r;
    if (xob) xob[idx] = __float2bfloat16(r);
  }
}

// ----------------------------------------------------------------- launch
extern "C" void kernel_launch(void* const* d_in, const int* in_sizes, int n_in,
                              void* d_out, int out_size, void* d_ws, size_t ws_size,
                              hipStream_t stream) {
  const float* x  = (const float*)d_in[0];
  const float* Wq = (const float*)d_in[1];
  const float* Wk = (const float*)d_in[2];
  const float* Wv = (const float*)d_in[3];
  const float* Wo = (const float*)d_in[4];
  const float* bo = (const float*)d_in[5];
  const float* W1 = (const float*)d_in[6];
  const float* b1 = (const float*)d_in[7];
  const float* W2 = (const float*)d_in[8];
  const float* b2 = (const float*)d_in[9];
  float* out = (float*)d_out;

  // ---- workspace map (no overlaps among simultaneously-live buffers)
  char* ws = (char*)d_ws;
  bf16* qkv_bf = (bf16*)(ws);                    //         0 .. 50,331,648  (48 MB)
  bf16* x_bf   = (bf16*)(ws + 50331648);         //  .. 67,108,864  (16 MB)
  bf16* WqkvT  = (bf16*)(ws + 67108864);         //  .. 73,400,320  (6 MB)
  bf16* WoT    = (bf16*)(ws + 73400320);         //  .. 75,497,472  (2 MB)
  bf16* W1T    = (bf16*)(ws + 75497472);         //  .. 83,886,080  (8 MB)
  bf16* W2T    = (bf16*)(ws + 83886080);         //  .. 92,274,688  (8 MB)
  bf16* o_bf   = (bf16*)(ws + 92274688);         //  .. 109,051,904 (16 MB)
  float* attn  = (float*)(ws + 109051904);       //  .. 142,606,336 (32 MB)
  float* x1    = (float*)(ws + 142606336);       //  .. 176,160,768 (32 MB)
  bf16* x1b    = (bf16*)(ws + 176160768);        //  .. 192,937,984 (16 MB)
  bf16* h1     = (bf16*)(ws);                    // 64 MB, reuses qkv_bf+x_bf (dead by FF)
  float* ff    = (float*)(ws + 109051904);       // 32 MB, reuses attn (dead after ln_res#1)

  // ---- input conversion / weight packing
  f32_to_bf16_k<<<8192, 256, 0, stream>>>(x, x_bf, (size_t)8388608);
  tr_to_bf16_k<<<dim3(2, 32, 16), 256, 0, stream>>>(Wq, WqkvT,               1024, 64,   65536, 65536);
  tr_to_bf16_k<<<dim3(2, 32, 16), 256, 0, stream>>>(Wk, WqkvT + 1024 * 1024, 1024, 64,   65536, 65536);
  tr_to_bf16_k<<<dim3(2, 32, 16), 256, 0, stream>>>(Wv, WqkvT + 2048 * 1024, 1024, 64,   65536, 65536);
  tr_to_bf16_k<<<dim3(32, 32, 1), 256, 0, stream>>>(Wo, WoT,                 1024, 1024, 0, 0);
  tr_to_bf16_k<<<dim3(128, 32, 1), 256, 0, stream>>>(W1, W1T,                1024, 4096, 0, 0);
  tr_to_bf16_k<<<dim3(32, 128, 1), 256, 0, stream>>>(W2, W2T,                4096, 1024, 0, 0);

  // ---- QKV projection, bf16 out, q pre-scaled by 0.125*log2(e)
  gemm_bt<0><<<dim3(24, 64), 256, 0, stream>>>(x_bf, WqkvT, nullptr, nullptr, qkv_bf, 8192, 3072, 1024);

  // ---- MFMA flash attention
  attn_mfma<<<dim3(16, 16, 4), 256, 0, stream>>>(qkv_bf, o_bf);

  // ---- output projection + bias
  gemm_bt<1><<<dim3(8, 64), 256, 0, stream>>>(o_bf, WoT, bo, attn, nullptr, 8192, 1024, 1024);

  // ---- x1 = x + LN(attn)
  ln_res<<<8192, 256, 0, stream>>>(x, attn, x1, x1b);

  // ---- FF
  gemm_bt<2><<<dim3(32, 64), 256, 0, stream>>>(x1b, W1T, b1, nullptr, h1, 8192, 4096, 1024);
  gemm_bt<1><<<dim3(8, 64), 256, 0, stream>>>(h1, W2T, b2, ff, nullptr, 8192, 1024, 4096);

  // ---- out = x1 + LN(ff)
  ln_res<<<8192, 256, 0, stream>>>(x1, ff, out, nullptr);
}